// Round 1
// baseline (610.852 us; speedup 1.0000x reference)
//
#include <hip/hip_runtime.h>

#define NCLS 19
#define NIMG 16
#define HW (512 * 512)
#define EPSV 1e-6f
#define PPB 2048              // pixels per block
#define BPI (HW / PPB)        // 128 blocks per image
#define NBINS (2 * NCLS)      // union[19] + inter[19] per block slot

// ---------------------------------------------------------------------------
// Kernel 1: per-pixel argmax over C for preds & targets.
// 8 pixels/thread (two float4 chunks 1024 pixels apart -> both loads are
// perfectly coalesced 1KB/wave), preds+targets interleaved in one class loop
// for 4 independent load streams (MLP). Histogram via the union identity:
//   union = |pred==c| + |targ==c| - inter  ==>  per pixel:
//   union[a]+=1;  a==b ? inter[a]+=1 : union[b]+=1     (2 atomics/pixel)
// Each block writes its own 38-counter slot: no zero-init, no global atomics,
// no memset dispatch (poison-safe).
// ---------------------------------------------------------------------------
__global__ __launch_bounds__(256, 4) void hist_kernel(
    const float* __restrict__ preds, const float* __restrict__ targs,
    int* __restrict__ partial /* [NIMG][BPI][NBINS] */)
{
    __shared__ int s_union[NCLS];
    __shared__ int s_inter[NCLS];

    const int t = threadIdx.x;
    if (t < NCLS) { s_union[t] = 0; s_inter[t] = 0; }
    __syncthreads();

    const int n = blockIdx.y;
    const long pixA  = (long)blockIdx.x * PPB + (long)t * 4;
    const long baseA = (long)n * NCLS * HW + pixA;
    const long baseB = baseA + 1024;   // second half of the block's 2048 pixels

    // class 0 init
    float4 p = *(const float4*)(preds + baseA);
    float4 q = *(const float4*)(preds + baseB);
    float4 x = *(const float4*)(targs + baseA);
    float4 y = *(const float4*)(targs + baseB);

    float pm0=p.x, pm1=p.y, pm2=p.z, pm3=p.w, pm4=q.x, pm5=q.y, pm6=q.z, pm7=q.w;
    float tm0=x.x, tm1=x.y, tm2=x.z, tm3=x.w, tm4=y.x, tm5=y.y, tm6=y.z, tm7=y.w;
    int   pa0=0, pa1=0, pa2=0, pa3=0, pa4=0, pa5=0, pa6=0, pa7=0;
    int   ta0=0, ta1=0, ta2=0, ta3=0, ta4=0, ta5=0, ta6=0, ta7=0;

#pragma unroll
    for (int c = 1; c < NCLS; ++c) {
        const long off = (long)c * HW;
        p = *(const float4*)(preds + baseA + off);
        q = *(const float4*)(preds + baseB + off);
        x = *(const float4*)(targs + baseA + off);
        y = *(const float4*)(targs + baseB + off);
        // strict > keeps the FIRST max: matches jnp.argmax tie-breaking
        if (p.x > pm0) { pm0 = p.x; pa0 = c; }
        if (p.y > pm1) { pm1 = p.y; pa1 = c; }
        if (p.z > pm2) { pm2 = p.z; pa2 = c; }
        if (p.w > pm3) { pm3 = p.w; pa3 = c; }
        if (q.x > pm4) { pm4 = q.x; pa4 = c; }
        if (q.y > pm5) { pm5 = q.y; pa5 = c; }
        if (q.z > pm6) { pm6 = q.z; pa6 = c; }
        if (q.w > pm7) { pm7 = q.w; pa7 = c; }
        if (x.x > tm0) { tm0 = x.x; ta0 = c; }
        if (x.y > tm1) { tm1 = x.y; ta1 = c; }
        if (x.z > tm2) { tm2 = x.z; ta2 = c; }
        if (x.w > tm3) { tm3 = x.w; ta3 = c; }
        if (y.x > tm4) { tm4 = y.x; ta4 = c; }
        if (y.y > tm5) { tm5 = y.y; ta5 = c; }
        if (y.z > tm6) { tm6 = y.z; ta6 = c; }
        if (y.w > tm7) { tm7 = y.w; ta7 = c; }
    }

    // 2 LDS atomics per pixel (branchless second target)
#define ACC(A, B) { atomicAdd(&s_union[A], 1);                                \
                    atomicAdd(((A) == (B)) ? &s_inter[A] : &s_union[B], 1); }
    ACC(pa0, ta0); ACC(pa1, ta1); ACC(pa2, ta2); ACC(pa3, ta3);
    ACC(pa4, ta4); ACC(pa5, ta5); ACC(pa6, ta6); ACC(pa7, ta7);
#undef ACC
    __syncthreads();

    if (t < NCLS) {
        int* dst = partial + ((long)n * BPI + blockIdx.x) * NBINS;
        dst[t]        = s_union[t];
        dst[NCLS + t] = s_inter[t];
    }
}

// ---------------------------------------------------------------------------
// Kernel 2: reduce 2048 block slots -> per-(n,c) totals -> weighted IoU mean.
// 311 KB of partials; single block, ~5 us.
// ---------------------------------------------------------------------------
__global__ __launch_bounds__(256) void finalize_kernel(
    const int* __restrict__ partial, const float* __restrict__ wts,
    float* __restrict__ out)
{
    __shared__ int tot[NIMG * NBINS];   // 608 ints

    const int t = threadIdx.x;
    for (int b = t; b < NIMG * NBINS; b += 256) {
        const int n = b / NBINS, k = b % NBINS;
        const int* src = partial + (long)n * BPI * NBINS + k;
        int s = 0;
#pragma unroll 4
        for (int blk = 0; blk < BPI; ++blk) s += src[(long)blk * NBINS];
        tot[b] = s;
    }
    __syncthreads();

    float sum = 0.f;
    for (int i = t; i < NIMG * NCLS; i += 256) {
        const int n = i / NCLS, c = i % NCLS;
        const float un = (float)tot[n * NBINS + c];
        const float ic = (float)tot[n * NBINS + NCLS + c];
        sum += wts[c] * (ic + EPSV) / (un + EPSV);
    }
#pragma unroll
    for (int off = 32; off > 0; off >>= 1) sum += __shfl_down(sum, off, 64);

    __shared__ float wsum[4];
    if ((t & 63) == 0) wsum[t >> 6] = sum;
    __syncthreads();
    if (t == 0)
        out[0] = (wsum[0] + wsum[1] + wsum[2] + wsum[3]) / (float)(NIMG * NCLS);
}

extern "C" void kernel_launch(void* const* d_in, const int* in_sizes, int n_in,
                              void* d_out, int out_size, void* d_ws, size_t ws_size,
                              hipStream_t stream) {
    const float* preds = (const float*)d_in[0];
    const float* targs = (const float*)d_in[1];
    const float* wts   = (const float*)d_in[2];

    int* partial = (int*)d_ws;   // NIMG*BPI*NBINS ints = 311,296 B, fully
                                 // overwritten each launch -> poison-safe.

    dim3 grid(BPI, NIMG);        // 128 x 16 = 2048 blocks
    hist_kernel<<<grid, 256, 0, stream>>>(preds, targs, partial);
    finalize_kernel<<<1, 256, 0, stream>>>(partial, wts, (float*)d_out);
}

// Round 2
// 599.393 us; speedup vs baseline: 1.0191x; 1.0191x over previous
//
#include <hip/hip_runtime.h>

#define NCLS 19
#define NIMG 16
#define HW (512 * 512)
#define EPSV 1e-6f
#define PPB 4096              // pixels per block
#define BPI (HW / PPB)        // 64 blocks per image
#define NBINS (2 * NCLS)      // union[19] + inter[19] per block slot

// ---------------------------------------------------------------------------
// 16-pixel argmax sweep over the 19 class planes for ONE tensor.
// Pixels live at base + {0,1024,2048,3072} + lane*4 -> the block touches a
// single 16KB contiguous span per (class, tensor) visit, and visits walk one
// tensor at a time in ascending address order (DRAM row locality).
// Strict > keeps the FIRST max: matches jnp.argmax tie-breaking.
// ---------------------------------------------------------------------------
__device__ __forceinline__ void argmax16(const float* __restrict__ p, long base,
                                         float* __restrict__ M, int* __restrict__ A)
{
    float4 v0 = *(const float4*)(p + base);
    float4 v1 = *(const float4*)(p + base + 1024);
    float4 v2 = *(const float4*)(p + base + 2048);
    float4 v3 = *(const float4*)(p + base + 3072);
    M[0] = v0.x; M[1] = v0.y; M[2]  = v0.z; M[3]  = v0.w;
    M[4] = v1.x; M[5] = v1.y; M[6]  = v1.z; M[7]  = v1.w;
    M[8] = v2.x; M[9] = v2.y; M[10] = v2.z; M[11] = v2.w;
    M[12]= v3.x; M[13]= v3.y; M[14] = v3.z; M[15] = v3.w;
#pragma unroll
    for (int i = 0; i < 16; ++i) A[i] = 0;

#pragma unroll
    for (int c = 1; c < NCLS; ++c) {
        const long off = base + (long)c * HW;
        v0 = *(const float4*)(p + off);
        v1 = *(const float4*)(p + off + 1024);
        v2 = *(const float4*)(p + off + 2048);
        v3 = *(const float4*)(p + off + 3072);
        if (v0.x > M[0])  { M[0]  = v0.x; A[0]  = c; }
        if (v0.y > M[1])  { M[1]  = v0.y; A[1]  = c; }
        if (v0.z > M[2])  { M[2]  = v0.z; A[2]  = c; }
        if (v0.w > M[3])  { M[3]  = v0.w; A[3]  = c; }
        if (v1.x > M[4])  { M[4]  = v1.x; A[4]  = c; }
        if (v1.y > M[5])  { M[5]  = v1.y; A[5]  = c; }
        if (v1.z > M[6])  { M[6]  = v1.z; A[6]  = c; }
        if (v1.w > M[7])  { M[7]  = v1.w; A[7]  = c; }
        if (v2.x > M[8])  { M[8]  = v2.x; A[8]  = c; }
        if (v2.y > M[9])  { M[9]  = v2.y; A[9]  = c; }
        if (v2.z > M[10]) { M[10] = v2.z; A[10] = c; }
        if (v2.w > M[11]) { M[11] = v2.w; A[11] = c; }
        if (v3.x > M[12]) { M[12] = v3.x; A[12] = c; }
        if (v3.y > M[13]) { M[13] = v3.y; A[13] = c; }
        if (v3.z > M[14]) { M[14] = v3.z; A[14] = c; }
        if (v3.w > M[15]) { M[15] = v3.w; A[15] = c; }
    }
}

// ---------------------------------------------------------------------------
// Kernel 1: per-pixel argmax + histogram, union identity (2 LDS atomics/px):
//   union[a]+=1;  a==b ? inter[a]+=1 : union[b]+=1
// Each block writes its private 38-counter slot (no memset, poison-safe).
// ---------------------------------------------------------------------------
__global__ __launch_bounds__(256, 4) void hist_kernel(
    const float* __restrict__ preds, const float* __restrict__ targs,
    int* __restrict__ partial /* [NIMG][BPI][NBINS] */)
{
    __shared__ int s_union[NCLS];
    __shared__ int s_inter[NCLS];

    const int t = threadIdx.x;
    if (t < NCLS) { s_union[t] = 0; s_inter[t] = 0; }
    __syncthreads();

    const int n = blockIdx.y;
    const long base = (long)n * NCLS * HW + (long)blockIdx.x * PPB + (long)t * 4;

    float pm[16]; int pa[16];
    argmax16(preds, base, pm, pa);          // sweep tensor 1, state -> pa
    float tm[16]; int ta[16];
    argmax16(targs, base, tm, ta);          // sweep tensor 2, state -> ta

#pragma unroll
    for (int i = 0; i < 16; ++i) {
        atomicAdd(&s_union[pa[i]], 1);
        atomicAdd((pa[i] == ta[i]) ? &s_inter[pa[i]] : &s_union[ta[i]], 1);
    }
    __syncthreads();

    if (t < NCLS) {
        int* dst = partial + ((long)n * BPI + blockIdx.x) * NBINS;
        dst[t]        = s_union[t];
        dst[NCLS + t] = s_inter[t];
    }
}

// ---------------------------------------------------------------------------
// Kernel 2: reduce 1024 block slots -> per-(n,c) totals -> weighted IoU mean.
// 155 KB of partials; single block, a few us.
// ---------------------------------------------------------------------------
__global__ __launch_bounds__(256) void finalize_kernel(
    const int* __restrict__ partial, const float* __restrict__ wts,
    float* __restrict__ out)
{
    __shared__ int tot[NIMG * NBINS];   // 608 ints

    const int t = threadIdx.x;
    for (int b = t; b < NIMG * NBINS; b += 256) {
        const int n = b / NBINS, k = b % NBINS;
        const int* src = partial + (long)n * BPI * NBINS + k;
        int s = 0;
#pragma unroll 4
        for (int blk = 0; blk < BPI; ++blk) s += src[(long)blk * NBINS];
        tot[b] = s;
    }
    __syncthreads();

    float sum = 0.f;
    for (int i = t; i < NIMG * NCLS; i += 256) {
        const int n = i / NCLS, c = i % NCLS;
        const float un = (float)tot[n * NBINS + c];
        const float ic = (float)tot[n * NBINS + NCLS + c];
        sum += wts[c] * (ic + EPSV) / (un + EPSV);
    }
#pragma unroll
    for (int off = 32; off > 0; off >>= 1) sum += __shfl_down(sum, off, 64);

    __shared__ float wsum[4];
    if ((t & 63) == 0) wsum[t >> 6] = sum;
    __syncthreads();
    if (t == 0)
        out[0] = (wsum[0] + wsum[1] + wsum[2] + wsum[3]) / (float)(NIMG * NCLS);
}

extern "C" void kernel_launch(void* const* d_in, const int* in_sizes, int n_in,
                              void* d_out, int out_size, void* d_ws, size_t ws_size,
                              hipStream_t stream) {
    const float* preds = (const float*)d_in[0];
    const float* targs = (const float*)d_in[1];
    const float* wts   = (const float*)d_in[2];

    int* partial = (int*)d_ws;   // NIMG*BPI*NBINS ints = 155,648 B, fully
                                 // overwritten each launch -> poison-safe.

    dim3 grid(BPI, NIMG);        // 64 x 16 = 1024 blocks
    hist_kernel<<<grid, 256, 0, stream>>>(preds, targs, partial);
    finalize_kernel<<<1, 256, 0, stream>>>(partial, wts, (float*)d_out);
}